// Round 1
// baseline (195.152 us; speedup 1.0000x reference)
//
#include <hip/hip_runtime.h>
#include <math.h>

#define HEADS 8
#define DIM   64
#define DH    64
#define DK    24
#define DHK   3
#define BB    4
#define HH    128
#define WW    128
#define NN    (HH*WW)        // 16384 tokens per batch
#define QSCALE 0.125f        // 1/sqrt(DIM)

// ---------------------------------------------------------------------------
// Kernel A: k_inp = illu_map @ Wk  (fused with)  S[b,j,c] += sum_n k_inp*x
// grid = 256 blocks (4 b x 64 chunks of 256 tokens), 256 threads
// ---------------------------------------------------------------------------
__global__ __launch_bounds__(256) void k_proj_reduce(
    const float* __restrict__ imap,   // [B*N, 24]
    const float* __restrict__ x,      // [B*N, 64]
    const float* __restrict__ Wk,     // [24, 24]
    float* __restrict__ k_inp,        // [B*N, 24]
    float* __restrict__ S)            // [B, 24, 64] (pre-zeroed)
{
    __shared__ float wk_l[24*24];
    __shared__ float kbuf[256*25];    // padded stride 25 (bank spread)

    const int tid   = threadIdx.x;
    const int blk   = blockIdx.x;
    const int b     = blk >> 6;
    const int chunk = blk & 63;
    const long base = (long)b * NN + (long)chunk * 256;   // token index base

    for (int i = tid; i < 576; i += 256) wk_l[i] = Wk[i];
    __syncthreads();

    // each thread projects one token: k[0..23] = m[0..23] @ Wk
    {
        const float4* m4 = (const float4*)(imap + (base + tid) * 24);
        float m[24];
        #pragma unroll
        for (int i = 0; i < 6; ++i) {
            float4 v = m4[i];
            m[4*i+0]=v.x; m[4*i+1]=v.y; m[4*i+2]=v.z; m[4*i+3]=v.w;
        }
        float kv[24];
        #pragma unroll
        for (int j = 0; j < 24; ++j) kv[j] = 0.f;
        for (int i = 0; i < 24; ++i) {
            float mi = m[i];
            #pragma unroll
            for (int j = 0; j < 24; ++j) kv[j] += mi * wk_l[i*24 + j];
        }
        #pragma unroll
        for (int j = 0; j < 24; ++j) kbuf[tid*25 + j] = kv[j];
    }
    __syncthreads();

    // coalesced write of k_inp for this chunk
    for (int e = tid; e < 256*24; e += 256) {
        int t = e / 24, j = e - t*24;
        k_inp[base*24 + e] = kbuf[t*25 + j];
    }

    // rank-1 accumulate S[j,c] += k[t,j]*x[t,c] over the 256 tokens.
    // thread owns 6 (j,c) pairs: c = tid&63 (lane -> coalesced / conflict-free),
    // j = (tid>>6) + 4p (wave-uniform -> LDS broadcast)
    const int c  = tid & 63;
    const int jb = tid >> 6;
    float acc[6] = {0.f,0.f,0.f,0.f,0.f,0.f};
    const float* xb = x + base * 64;
    for (int tok = 0; tok < 256; ++tok) {
        float xv = xb[tok*64 + c];
        #pragma unroll
        for (int p = 0; p < 6; ++p)
            acc[p] += kbuf[tok*25 + jb + 4*p] * xv;
    }
    float* Sb = S + b * (24*64);
    #pragma unroll
    for (int p = 0; p < 6; ++p)
        atomicAdd(&Sb[(jb + 4*p)*64 + c], acc[p]);
}

// ---------------------------------------------------------------------------
// Kernel B: per-batch tiny stage: attn = softmax(S@Wq/8 * rescale),
//           M = attn @ Wv(cols), P = M^T(reordered) @ Wp.  grid = 4 blocks.
// ---------------------------------------------------------------------------
__global__ __launch_bounds__(256) void attn_p(
    const float* __restrict__ S,       // [B,24,64]
    const float* __restrict__ Wq,      // [64, 512]
    const float* __restrict__ Wv,      // [64, 512]
    const float* __restrict__ rescale, // [8]
    const float* __restrict__ Wp,      // [24, 24]
    float* __restrict__ P)             // [B, 64, 24]
{
    __shared__ float S_l[24*64];
    __shared__ float att[24*64];
    __shared__ float M_l[24*64];
    __shared__ float wp_l[576];

    const int b = blockIdx.x;
    const int tid = threadIdx.x;

    for (int i = tid; i < 1536; i += 256) S_l[i] = S[b*1536 + i];
    for (int i = tid; i < 576;  i += 256) wp_l[i] = Wp[i];
    __syncthreads();

    // attn_pre[ch][d] = (1/8)*rescale[h] * sum_c S[ch][c]*Wq[c][h*64+d]
    for (int q = tid; q < 1536; q += 256) {
        int d = q & 63, ch = q >> 6;     // ch = h*3 + k
        int h = ch / 3;
        const float* wq = Wq + h*64 + d; // column, stride 512 (lanes d -> coalesced)
        const float* sr = S_l + ch*64;
        float s = 0.f;
        for (int cc = 0; cc < 64; ++cc) s += sr[cc] * wq[cc*512];
        att[q] = s * QSCALE * rescale[h];
    }
    __syncthreads();

    // softmax over d per row (24 rows — trivial serial per thread)
    if (tid < 24) {
        float* row = att + tid*64;
        float mx = row[0];
        for (int d = 1; d < 64; ++d) mx = fmaxf(mx, row[d]);
        float sum = 0.f;
        for (int d = 0; d < 64; ++d) { float e = expf(row[d]-mx); row[d] = e; sum += e; }
        float inv = 1.f / sum;
        for (int d = 0; d < 64; ++d) row[d] *= inv;
    }
    __syncthreads();

    // M[ch][c] = sum_d att[ch][d] * Wv[c][h*64+d]
    for (int q = tid; q < 1536; q += 256) {
        int c = q & 63, ch = q >> 6;
        int h = ch / 3;
        const float* wv = Wv + c*512 + h*64;
        const float* ar = att + ch*64;
        float s = 0.f;
        for (int d = 0; d < 64; ++d) s += ar[d] * wv[d];
        M_l[ch*64 + c] = s;
    }
    __syncthreads();

    // P[c][jo] = sum_{k,h} M[(h*3+k)][c] * Wp[(k*8+h)][jo]
    for (int q = tid; q < 64*24; q += 256) {
        int c = q / 24, jo = q - c*24;
        float s = 0.f;
        #pragma unroll
        for (int k = 0; k < 3; ++k)
            #pragma unroll
            for (int h = 0; h < 8; ++h)
                s += M_l[(h*3+k)*64 + c] * wp_l[(k*8+h)*24 + jo];
        P[b*1536 + q] = s;
    }
}

// ---------------------------------------------------------------------------
// Kernel C: y1 = gelu_exact(gconv3x3(k_inp, conv1_w)), groups=3, NHWC.
// grid = 4*16*16 blocks, 8x8 spatial tile x 24 ch per block.
// ---------------------------------------------------------------------------
__global__ __launch_bounds__(256) void conv1_gelu(
    const float* __restrict__ k_inp,  // [B,128,128,24]
    const float* __restrict__ cw,     // [24,8,3,3] OIHW
    float* __restrict__ y1)           // [B,128,128,24]
{
    __shared__ float in_l[100*25];    // 10x10 halo tile, pixel stride 25
    __shared__ float w_l[24*8*9];
    __shared__ float obuf[64*25];

    const int tid = threadIdx.x;
    const int blk = blockIdx.x;
    const int b  = blk >> 8;
    const int ti = (blk >> 4) & 15, tj = blk & 15;
    const int i0 = ti*8, j0 = tj*8;

    for (int i = tid; i < 1728; i += 256) w_l[i] = cw[i];
    for (int idx = tid; idx < 2400; idx += 256) {
        int pix = idx / 24, cch = idx - pix*24;
        int ii = pix / 10, jj = pix - ii*10;
        int gi = i0 + ii - 1, gj = j0 + jj - 1;
        float v = 0.f;
        if (gi >= 0 && gi < HH && gj >= 0 && gj < WW)
            v = k_inp[(((long)b*HH + gi)*WW + gj)*24 + cch];
        in_l[pix*25 + cch] = v;
    }
    __syncthreads();

    const int pos = tid & 63;
    const int ii = pos >> 3, jj = pos & 7;
    const int ob = tid >> 6;           // wave-uniform channel base
    #pragma unroll
    for (int p = 0; p < 6; ++p) {
        int o = ob + 4*p;
        int g = o >> 3;
        const float* wo = w_l + o*72;
        float s = 0.f;
        #pragma unroll
        for (int di = 0; di < 3; ++di)
            #pragma unroll
            for (int dj = 0; dj < 3; ++dj) {
                const float* ip = in_l + ((ii+di)*10 + (jj+dj))*25 + g*8;
                #pragma unroll
                for (int ic = 0; ic < 8; ++ic)
                    s += ip[ic] * wo[ic*9 + di*3 + dj];
            }
        obuf[pos*25 + o] = s * 0.5f * (1.f + erff(s * 0.70710678f));
    }
    __syncthreads();

    for (int e = tid; e < 1536; e += 256) {
        int row = e / 192, rem = e - row*192;
        int pix = row*8 + rem/24;
        int ch  = rem - (rem/24)*24;
        y1[(((long)b*HH + i0+row)*WW + j0)*24 + rem] = obuf[pix*25 + ch];
    }
}

// ---------------------------------------------------------------------------
// Kernel D: out = illu_fea @ P[b] + bp + gconv3x3(y1, conv2_w)
// ---------------------------------------------------------------------------
__global__ __launch_bounds__(256) void conv2_proj_out(
    const float* __restrict__ y1,     // [B,128,128,24]
    const float* __restrict__ fea,    // [B*N, 64]
    const float* __restrict__ cw2,    // [24,8,3,3]
    const float* __restrict__ P,      // [B,64,24]
    const float* __restrict__ bp,     // [24]
    float* __restrict__ out)          // [B,128,128,24]
{
    __shared__ float in_l[100*25];
    __shared__ float w_l[24*8*9];
    __shared__ float P_l[64*24];
    __shared__ float bp_l[24];
    __shared__ float fea_l[64*65];    // 64 pixels x 64 ch, stride 65
    __shared__ float obuf[64*25];

    const int tid = threadIdx.x;
    const int blk = blockIdx.x;
    const int b  = blk >> 8;
    const int ti = (blk >> 4) & 15, tj = blk & 15;
    const int i0 = ti*8, j0 = tj*8;

    for (int i = tid; i < 1728; i += 256) w_l[i] = cw2[i];
    for (int i = tid; i < 1536; i += 256) P_l[i] = P[b*1536 + i];
    if (tid < 24) bp_l[tid] = bp[tid];
    for (int idx = tid; idx < 2400; idx += 256) {
        int pix = idx / 24, cch = idx - pix*24;
        int ii = pix / 10, jj = pix - ii*10;
        int gi = i0 + ii - 1, gj = j0 + jj - 1;
        float v = 0.f;
        if (gi >= 0 && gi < HH && gj >= 0 && gj < WW)
            v = y1[(((long)b*HH + gi)*WW + gj)*24 + cch];
        in_l[pix*25 + cch] = v;
    }
    for (int idx = tid; idx < 4096; idx += 256) {
        int pix = idx >> 6, c = idx & 63;
        int gi = i0 + (pix >> 3), gj = j0 + (pix & 7);
        fea_l[pix*65 + c] = fea[(((long)b*HH + gi)*WW + gj)*64 + c];
    }
    __syncthreads();

    const int pos = tid & 63;
    const int ii = pos >> 3, jj = pos & 7;
    const int ob = tid >> 6;

    // projection part: accs[p] = bp[o] + sum_c fea[pos][c] * P[c][o]
    float accs[6];
    #pragma unroll
    for (int p = 0; p < 6; ++p) accs[p] = bp_l[ob + 4*p];
    for (int c = 0; c < 64; ++c) {
        float fv = fea_l[pos*65 + c];
        #pragma unroll
        for (int p = 0; p < 6; ++p)
            accs[p] += fv * P_l[c*24 + ob + 4*p];
    }
    // conv2 part
    #pragma unroll
    for (int p = 0; p < 6; ++p) {
        int o = ob + 4*p;
        int g = o >> 3;
        const float* wo = w_l + o*72;
        float s = 0.f;
        #pragma unroll
        for (int di = 0; di < 3; ++di)
            #pragma unroll
            for (int dj = 0; dj < 3; ++dj) {
                const float* ip = in_l + ((ii+di)*10 + (jj+dj))*25 + g*8;
                #pragma unroll
                for (int ic = 0; ic < 8; ++ic)
                    s += ip[ic] * wo[ic*9 + di*3 + dj];
            }
        obuf[pos*25 + o] = accs[p] + s;
    }
    __syncthreads();

    for (int e = tid; e < 1536; e += 256) {
        int row = e / 192, rem = e - row*192;
        int pix = row*8 + rem/24;
        int ch  = rem - (rem/24)*24;
        out[(((long)b*HH + i0+row)*WW + j0)*24 + rem] = obuf[pix*25 + ch];
    }
}

// ---------------------------------------------------------------------------
extern "C" void kernel_launch(void* const* d_in, const int* in_sizes, int n_in,
                              void* d_out, int out_size, void* d_ws, size_t ws_size,
                              hipStream_t stream) {
    const float* x_in    = (const float*)d_in[0];
    const float* fea     = (const float*)d_in[1];
    const float* imap    = (const float*)d_in[2];
    const float* Wq      = (const float*)d_in[3];
    const float* Wk      = (const float*)d_in[4];
    const float* Wv      = (const float*)d_in[5];
    const float* rescale = (const float*)d_in[6];
    const float* Wp      = (const float*)d_in[7];
    const float* bp      = (const float*)d_in[8];
    const float* c1w     = (const float*)d_in[9];
    const float* c2w     = (const float*)d_in[10];
    float* out = (float*)d_out;

    float* ws    = (float*)d_ws;
    float* k_inp = ws;                       // 4*16384*24 = 1,572,864 floats
    float* y1    = ws + 1572864;             // 1,572,864 floats
    float* S     = ws + 3145728;             // 4*24*64 = 6144 floats
    float* P     = ws + 3151872;             // 4*64*24 = 6144 floats

    hipMemsetAsync(S, 0, 6144*sizeof(float), stream);
    k_proj_reduce<<<256, 256, 0, stream>>>(imap, x_in, Wk, k_inp, S);
    attn_p<<<4, 256, 0, stream>>>(S, Wq, Wv, rescale, Wp, P);
    conv1_gelu<<<BB*16*16, 256, 0, stream>>>(k_inp, c1w, y1);
    conv2_proj_out<<<BB*16*16, 256, 0, stream>>>(y1, fea, c2w, P, bp, out);
}

// Round 3
// 182.643 us; speedup vs baseline: 1.0685x; 1.0685x over previous
//
#include <hip/hip_runtime.h>
#include <math.h>

#define HEADS 8
#define DIM   64
#define DK    24
#define DHK   3
#define BB    4
#define HH    128
#define WW    128
#define NN    (HH*WW)
#define QSCALE 0.125f

// ---------------------------------------------------------------------------
// K1: S'[b,i,c] = sum_n imap[b,n,i] * x[b,n,c]   (24x64 per batch)
// grid 512 (4b x 128 chunks of 128 tokens), 256 threads.
// ---------------------------------------------------------------------------
__global__ __launch_bounds__(256) void s_reduce(
    const float* __restrict__ imap,   // [B*N,24]
    const float* __restrict__ x,      // [B*N,64]
    float* __restrict__ Sp)           // [B,24,64] pre-zeroed
{
    __shared__ float part[4*1536];
    const int tid = threadIdx.x;
    const int blk = blockIdx.x;
    const int b = blk >> 7, chunk = blk & 127;
    const int w = tid >> 6, lane = tid & 63;
    const int cq = lane & 15;         // c = cq*4
    const int ig = lane >> 4;         // i = ig*6 .. +5

    const long tok0 = (long)b * NN + chunk * 128 + w * 32;
    const float* xp = x    + tok0 * 64 + cq * 4;
    const float* mp = imap + tok0 * 24 + ig * 6;

    float acc[6][4];
    #pragma unroll
    for (int r = 0; r < 6; ++r)
        #pragma unroll
        for (int q = 0; q < 4; ++q) acc[r][q] = 0.f;

    for (int t = 0; t < 32; ++t) {
        float4 xv = *(const float4*)(xp + t * 64);
        float2 m0 = *(const float2*)(mp + t * 24);
        float2 m1 = *(const float2*)(mp + t * 24 + 2);
        float2 m2 = *(const float2*)(mp + t * 24 + 4);
        float mm[6] = {m0.x, m0.y, m1.x, m1.y, m2.x, m2.y};
        #pragma unroll
        for (int r = 0; r < 6; ++r) {
            acc[r][0] += mm[r] * xv.x;
            acc[r][1] += mm[r] * xv.y;
            acc[r][2] += mm[r] * xv.z;
            acc[r][3] += mm[r] * xv.w;
        }
    }

    float* pp = part + w * 1536;
    #pragma unroll
    for (int r = 0; r < 6; ++r) {
        float4 v = {acc[r][0], acc[r][1], acc[r][2], acc[r][3]};
        *(float4*)(pp + (ig * 6 + r) * 64 + cq * 4) = v;
    }
    __syncthreads();

    for (int e = tid; e < 1536; e += 256) {
        float s = part[e] + part[1536 + e] + part[3072 + e] + part[4608 + e];
        atomicAdd(&Sp[b * 1536 + e], s);
    }
}

// ---------------------------------------------------------------------------
// K2: S = Wk^T S'; attn = softmax(S@Wq * scale * rescale); M = attn@Wv;
//     Pt[b,o,c] = P[c,o].  grid 4 blocks.
// ---------------------------------------------------------------------------
__global__ __launch_bounds__(256) void attn_p(
    const float* __restrict__ Sp,      // [B,24,64]
    const float* __restrict__ Wk,      // [24,24]
    const float* __restrict__ Wq,      // [64,512]
    const float* __restrict__ Wv,      // [64,512]
    const float* __restrict__ rescale, // [8]
    const float* __restrict__ Wp,      // [24,24]
    float* __restrict__ Pt)            // [B,24,64]  (Pt[o][c] = P[c][o])
{
    __shared__ float Sp_l[1536];
    __shared__ float S_l[1536];
    __shared__ float att[1536];
    __shared__ float M_l[1536];

    const int b = blockIdx.x, tid = threadIdx.x;

    for (int i = tid; i < 1536; i += 256) Sp_l[i] = Sp[b * 1536 + i];
    __syncthreads();

    // S[j,c] = sum_i Wk[i,j]*Sp[i,c]
    for (int q = tid; q < 1536; q += 256) {
        int c = q & 63, j = q >> 6;
        float s = 0.f;
        #pragma unroll
        for (int i = 0; i < 24; ++i) s += Wk[i * 24 + j] * Sp_l[i * 64 + c];
        S_l[q] = s;
    }
    __syncthreads();

    // att_pre[ch][d]
    for (int q = tid; q < 1536; q += 256) {
        int d = q & 63, ch = q >> 6;
        int h = ch / 3;
        const float* wq = Wq + h * 64 + d;
        const float* sr = S_l + ch * 64;
        float s = 0.f;
        for (int cc = 0; cc < 64; ++cc) s += sr[cc] * wq[cc * 512];
        att[q] = s * QSCALE * rescale[h];
    }
    __syncthreads();

    if (tid < 24) {
        float* row = att + tid * 64;
        float mx = row[0];
        for (int d = 1; d < 64; ++d) mx = fmaxf(mx, row[d]);
        float sum = 0.f;
        for (int d = 0; d < 64; ++d) { float e = expf(row[d] - mx); row[d] = e; sum += e; }
        float inv = 1.f / sum;
        for (int d = 0; d < 64; ++d) row[d] *= inv;
    }
    __syncthreads();

    // M[ch][c] = sum_d att[ch][d]*Wv[c, h*64+d]
    for (int q = tid; q < 1536; q += 256) {
        int c = q & 63, ch = q >> 6;
        int h = ch / 3;
        const float* wv = Wv + c * 512 + h * 64;
        const float* ar = att + ch * 64;
        float s = 0.f;
        for (int d = 0; d < 64; ++d) s += ar[d] * wv[d];
        M_l[ch * 64 + c] = s;
    }
    __syncthreads();

    // Pt[jo][c] = sum_{k,h} M[(h*3+k)][c] * Wp[(k*8+h)][jo]
    for (int q = tid; q < 1536; q += 256) {
        int c = q & 63, jo = q >> 6;
        float s = 0.f;
        #pragma unroll
        for (int k = 0; k < 3; ++k)
            #pragma unroll
            for (int h = 0; h < 8; ++h)
                s += M_l[(h * 3 + k) * 64 + c] * Wp[(k * 8 + h) * 24 + jo];
        Pt[b * 1536 + q] = s;
    }
}

// ---------------------------------------------------------------------------
// K3: k_inp = imap @ Wk. One token/thread.
// ---------------------------------------------------------------------------
__global__ __launch_bounds__(256) void k_proj(
    const float* __restrict__ imap, const float* __restrict__ Wk,
    float* __restrict__ k_inp)
{
    __shared__ float kbuf[256 * 25];
    const int tid = threadIdx.x;
    const long base = (long)blockIdx.x * 256;

    const float4* m4 = (const float4*)(imap + (base + tid) * 24);
    float m[24];
    #pragma unroll
    for (int i = 0; i < 6; ++i) {
        float4 v = m4[i];
        m[4*i+0]=v.x; m[4*i+1]=v.y; m[4*i+2]=v.z; m[4*i+3]=v.w;
    }
    float kv[24];
    #pragma unroll
    for (int j = 0; j < 24; ++j) kv[j] = 0.f;
    for (int i = 0; i < 24; ++i) {
        float mi = m[i];
        #pragma unroll
        for (int j = 0; j < 24; ++j) kv[j] += mi * Wk[i * 24 + j];
    }
    #pragma unroll
    for (int j = 0; j < 24; ++j) kbuf[tid * 25 + j] = kv[j];
    __syncthreads();

    for (int e = tid; e < 6144; e += 256)
        k_inp[base * 24 + e] = kbuf[(e / 24) * 25 + (e % 24)];
}

// ---------------------------------------------------------------------------
// K4/K6 conv: 8x8 tile, 192 threads, thread=(o, jj). Sliding 3x3x8 register
// window; weights register-resident as wr[ic][di*3+dj] matching OIHW linear
// layout (R2 bug: was wr[di*3+dj][ic] — transposed).
// ---------------------------------------------------------------------------
template <bool GELU, bool ACCUM>
__device__ __forceinline__ void gconv_body(
    const float* __restrict__ in, const float* __restrict__ cw,
    float* __restrict__ outp)
{
    const int tid = threadIdx.x;
    const int o = tid % 24, jj = tid / 24;      // jj 0..7
    const int blk = blockIdx.x;
    const int b = blk >> 8, ti = (blk >> 4) & 15, tj = blk & 15;
    const int i0 = ti * 8, j0 = tj * 8;
    const int g = o >> 3;

    float wr[8][9];   // wr[ic][di*3+dj]; contiguous load matches OIHW slice
    {
        const float4* wp = (const float4*)(cw + o * 72);
        #pragma unroll
        for (int t = 0; t < 18; ++t) ((float4*)wr)[t] = wp[t];
    }

    const int gj0 = j0 + jj - 1;
    const bool cok0 = gj0 >= 0;
    const bool cok2 = (j0 + jj + 1) < WW;
    const float* basep = in + (long)b * NN * 24 + g * 8;

    float win[3][3][8];   // [row slot][dj][ic]

    #define LOADROW(GI, SLOT)                                                 \
    {                                                                         \
        const int gi_ = (GI);                                                 \
        const bool rok_ = (gi_ >= 0) & (gi_ < HH);                            \
        const float* rp_ = basep + ((long)gi_ * WW + gj0) * 24;               \
        float4 z_ = {0.f,0.f,0.f,0.f};                                        \
        float4 a0_=z_, a1_=z_, b0_=z_, b1_=z_, c0_=z_, c1_=z_;                \
        if (rok_ & cok0) { a0_ = *(const float4*)(rp_);                       \
                           a1_ = *(const float4*)(rp_ + 4); }                 \
        if (rok_)        { b0_ = *(const float4*)(rp_ + 24);                  \
                           b1_ = *(const float4*)(rp_ + 28); }                \
        if (rok_ & cok2) { c0_ = *(const float4*)(rp_ + 48);                  \
                           c1_ = *(const float4*)(rp_ + 52); }                \
        *(float4*)&win[SLOT][0][0] = a0_; *(float4*)&win[SLOT][0][4] = a1_;   \
        *(float4*)&win[SLOT][1][0] = b0_; *(float4*)&win[SLOT][1][4] = b1_;   \
        *(float4*)&win[SLOT][2][0] = c0_; *(float4*)&win[SLOT][2][4] = c1_;   \
    }

    LOADROW(i0 - 1, 0)
    LOADROW(i0,     1)

    #pragma unroll
    for (int ii = 0; ii < 8; ++ii) {
        LOADROW(i0 + ii + 1, (ii + 2) % 3)
        float s = 0.f;
        #pragma unroll
        for (int di = 0; di < 3; ++di) {
            const int slot = (ii + di) % 3;
            #pragma unroll
            for (int dj = 0; dj < 3; ++dj)
                #pragma unroll
                for (int ic = 0; ic < 8; ++ic)
                    s += win[slot][dj][ic] * wr[ic][di * 3 + dj];
        }
        if (GELU) s = 0.5f * s * (1.f + erff(s * 0.70710678f));
        const long idx = ((long)((b * HH + i0 + ii) * WW + j0)) * 24 + tid;
        if (ACCUM) outp[idx] = outp[idx] + s;
        else       outp[idx] = s;
    }
    #undef LOADROW
}

__global__ __launch_bounds__(192, 2) void conv1_gelu(
    const float* __restrict__ kin, const float* __restrict__ cw,
    float* __restrict__ y1)
{
    gconv_body<true, false>(kin, cw, y1);
}

__global__ __launch_bounds__(192, 2) void conv2_add(
    const float* __restrict__ y1, const float* __restrict__ cw,
    float* __restrict__ outp)
{
    gconv_body<false, true>(y1, cw, outp);
}

// ---------------------------------------------------------------------------
// K5: out = fea @ P[b] + bp.  grid 256, 256 thr.
// ---------------------------------------------------------------------------
__global__ __launch_bounds__(256) void proj_out(
    const float* __restrict__ fea,   // [B*N,64]
    const float* __restrict__ Pt,    // [B,24,64]
    const float* __restrict__ bp,    // [24]
    float* __restrict__ outp)        // [B*N,24]
{
    __shared__ float Pt_l[1536];
    __shared__ float obuf[256 * 25];

    const int tid = threadIdx.x;
    const int blk = blockIdx.x;
    const int b = blk >> 6, tile = blk & 63;
    const long pix0 = (long)b * NN + tile * 256;

    for (int e = tid; e < 1536; e += 256) Pt_l[e] = Pt[b * 1536 + e];
    __syncthreads();

    const int lane = tid & 63, og = tid >> 6;   // o = og*6 .. +5

    float acc[4][6];
    #pragma unroll
    for (int k = 0; k < 4; ++k)
        #pragma unroll
        for (int r = 0; r < 6; ++r) acc[k][r] = 0.f;

    const float* f0 = fea + (pix0 + lane) * 64;

    for (int cq = 0; cq < 16; ++cq) {
        float4 f[4];
        #pragma unroll
        for (int k = 0; k < 4; ++k)
            f[k] = *(const float4*)(f0 + 4096 * k + cq * 4);
        #pragma unroll
        for (int r = 0; r < 6; ++r) {
            float4 p = *(const float4*)(Pt_l + (og * 6 + r) * 64 + cq * 4);
            #pragma unroll
            for (int k = 0; k < 4; ++k) {
                acc[k][r] += f[k].x * p.x;
                acc[k][r] += f[k].y * p.y;
                acc[k][r] += f[k].z * p.z;
                acc[k][r] += f[k].w * p.w;
            }
        }
    }

    float bias[6];
    #pragma unroll
    for (int r = 0; r < 6; ++r) bias[r] = bp[og * 6 + r];

    #pragma unroll
    for (int k = 0; k < 4; ++k)
        #pragma unroll
        for (int r = 0; r < 6; ++r)
            obuf[(lane + 64 * k) * 25 + og * 6 + r] = acc[k][r] + bias[r];
    __syncthreads();

    for (int e = tid; e < 6144; e += 256)
        outp[pix0 * 24 + e] = obuf[(e / 24) * 25 + (e % 24)];
}

// ---------------------------------------------------------------------------
extern "C" void kernel_launch(void* const* d_in, const int* in_sizes, int n_in,
                              void* d_out, int out_size, void* d_ws, size_t ws_size,
                              hipStream_t stream) {
    const float* x_in    = (const float*)d_in[0];
    const float* fea     = (const float*)d_in[1];
    const float* imap    = (const float*)d_in[2];
    const float* Wq      = (const float*)d_in[3];
    const float* Wk      = (const float*)d_in[4];
    const float* Wv      = (const float*)d_in[5];
    const float* rescale = (const float*)d_in[6];
    const float* Wp      = (const float*)d_in[7];
    const float* bp      = (const float*)d_in[8];
    const float* c1w     = (const float*)d_in[9];
    const float* c2w     = (const float*)d_in[10];
    float* out = (float*)d_out;

    float* ws    = (float*)d_ws;
    float* k_inp = ws;                 // 1,572,864 floats
    float* y1    = ws + 1572864;       // 1,572,864 floats
    float* Sp    = ws + 3145728;       // 6144
    float* Pt    = ws + 3151872;       // 6144

    hipMemsetAsync(Sp, 0, 6144 * sizeof(float), stream);
    s_reduce<<<512, 256, 0, stream>>>(imap, x_in, Sp);
    attn_p<<<4, 256, 0, stream>>>(Sp, Wk, Wq, Wv, rescale, Wp, Pt);
    k_proj<<<256, 256, 0, stream>>>(imap, Wk, k_inp);
    conv1_gelu<<<BB * 256, 192, 0, stream>>>(k_inp, c1w, y1);
    proj_out<<<256, 256, 0, stream>>>(fea, Pt, bp, out);
    conv2_add<<<BB * 256, 192, 0, stream>>>(y1, c2w, out);
}

// Round 4
// 178.758 us; speedup vs baseline: 1.0917x; 1.0217x over previous
//
#include <hip/hip_runtime.h>
#include <math.h>

#define HEADS 8
#define DIM   64
#define DK    24
#define DHK   3
#define BB    4
#define HH    128
#define WW    128
#define NN    (HH*WW)
#define QSCALE 0.125f

// ---------------------------------------------------------------------------
// K1: fused  (a) Sp_part[blk] = sum over this block's 128 tokens of
//            imap[n,i]*x[n,c]  (24x64 partial)
//            (b) k_inp = imap @ Wk for the same 128 tokens.
// grid 512 (4b x 128 chunks of 128 tokens), 256 threads.
// ---------------------------------------------------------------------------
__global__ __launch_bounds__(256) void s_reduce_kproj(
    const float* __restrict__ imap,   // [B*N,24]
    const float* __restrict__ x,      // [B*N,64]
    const float* __restrict__ Wk,     // [24,24]
    float* __restrict__ k_inp,        // [B*N,24]
    float* __restrict__ Sp_part)      // [512,1536]
{
    __shared__ float lds[4*1536];     // phase1: part[4][1536]; phase2: kbuf 128*25
    const int tid = threadIdx.x;
    const int blk = blockIdx.x;
    const int b = blk >> 7, chunk = blk & 127;
    const int w = tid >> 6, lane = tid & 63;
    const int cq = lane & 15;         // c = cq*4
    const int ig = lane >> 4;         // i = ig*6 .. +5

    const long tokB = (long)b * NN + chunk * 128;
    const long tok0 = tokB + w * 32;
    const float* xp = x    + tok0 * 64 + cq * 4;
    const float* mp = imap + tok0 * 24 + ig * 6;

    float acc[6][4];
    #pragma unroll
    for (int r = 0; r < 6; ++r)
        #pragma unroll
        for (int q = 0; q < 4; ++q) acc[r][q] = 0.f;

    for (int t = 0; t < 32; ++t) {
        float4 xv = *(const float4*)(xp + t * 64);
        float2 m0 = *(const float2*)(mp + t * 24);
        float2 m1 = *(const float2*)(mp + t * 24 + 2);
        float2 m2 = *(const float2*)(mp + t * 24 + 4);
        float mm[6] = {m0.x, m0.y, m1.x, m1.y, m2.x, m2.y};
        #pragma unroll
        for (int r = 0; r < 6; ++r) {
            acc[r][0] += mm[r] * xv.x;
            acc[r][1] += mm[r] * xv.y;
            acc[r][2] += mm[r] * xv.z;
            acc[r][3] += mm[r] * xv.w;
        }
    }

    float* pp = lds + w * 1536;
    #pragma unroll
    for (int r = 0; r < 6; ++r) {
        float4 v = {acc[r][0], acc[r][1], acc[r][2], acc[r][3]};
        *(float4*)(pp + (ig * 6 + r) * 64 + cq * 4) = v;
    }
    __syncthreads();

    for (int e = tid; e < 1536; e += 256)
        Sp_part[(long)blk * 1536 + e] =
            lds[e] + lds[1536 + e] + lds[3072 + e] + lds[4608 + e];

    // ---- phase 2: k_inp for the same 128 tokens (threads 0..127) ----
    float kv[24];
    if (tid < 128) {
        const float4* m4 = (const float4*)(imap + (tokB + tid) * 24);
        float m[24];
        #pragma unroll
        for (int i = 0; i < 6; ++i) {
            float4 v = m4[i];
            m[4*i+0]=v.x; m[4*i+1]=v.y; m[4*i+2]=v.z; m[4*i+3]=v.w;
        }
        #pragma unroll
        for (int j = 0; j < 24; ++j) kv[j] = 0.f;
        for (int i = 0; i < 24; ++i) {
            float mi = m[i];
            #pragma unroll
            for (int j = 0; j < 24; ++j) kv[j] += mi * Wk[i * 24 + j];
        }
    }
    __syncthreads();   // all reads of lds (Sp_part loop) done
    if (tid < 128) {
        #pragma unroll
        for (int j = 0; j < 24; ++j) lds[tid * 25 + j] = kv[j];
    }
    __syncthreads();
    for (int e = tid; e < 128 * 24; e += 256)
        k_inp[tokB * 24 + e] = lds[(e / 24) * 25 + (e % 24)];
}

// ---------------------------------------------------------------------------
// K2: Sp[b][e] = sum over 128 chunk-partials. grid 24 (4b x 6), 256 thr.
// ---------------------------------------------------------------------------
__global__ __launch_bounds__(256) void sp_reduce(
    const float* __restrict__ Sp_part, float* __restrict__ Sp)
{
    const int blk = blockIdx.x;
    const int b = blk / 6, eb = blk % 6;
    const int e = eb * 256 + threadIdx.x;
    const float* p = Sp_part + (long)b * 128 * 1536 + e;
    float s0 = 0.f, s1 = 0.f, s2 = 0.f, s3 = 0.f;
    for (int c = 0; c < 128; c += 4) {
        s0 += p[(long)(c + 0) * 1536];
        s1 += p[(long)(c + 1) * 1536];
        s2 += p[(long)(c + 2) * 1536];
        s3 += p[(long)(c + 3) * 1536];
    }
    Sp[b * 1536 + e] = (s0 + s1) + (s2 + s3);
}

// ---------------------------------------------------------------------------
// K3: S = Wk^T Sp; attn = softmax(S@Wq * scale * rescale); M = attn@Wv;
//     Pt[b,o,c] = P[c,o].  grid 4 blocks.  (unchanged math from R3-pass)
// ---------------------------------------------------------------------------
__global__ __launch_bounds__(256) void attn_p(
    const float* __restrict__ Sp,      // [B,24,64]
    const float* __restrict__ Wk,      // [24,24]
    const float* __restrict__ Wq,      // [64,512]
    const float* __restrict__ Wv,      // [64,512]
    const float* __restrict__ rescale, // [8]
    const float* __restrict__ Wp,      // [24,24]
    float* __restrict__ Pt)            // [B,24,64]
{
    __shared__ float Sp_l[1536];
    __shared__ float S_l[1536];
    __shared__ float att[1536];
    __shared__ float M_l[1536];

    const int b = blockIdx.x, tid = threadIdx.x;

    for (int i = tid; i < 1536; i += 256) Sp_l[i] = Sp[b * 1536 + i];
    __syncthreads();

    for (int q = tid; q < 1536; q += 256) {
        int c = q & 63, j = q >> 6;
        float s = 0.f;
        #pragma unroll
        for (int i = 0; i < 24; ++i) s += Wk[i * 24 + j] * Sp_l[i * 64 + c];
        S_l[q] = s;
    }
    __syncthreads();

    for (int q = tid; q < 1536; q += 256) {
        int d = q & 63, ch = q >> 6;
        int h = ch / 3;
        const float* wq = Wq + h * 64 + d;
        const float* sr = S_l + ch * 64;
        float s = 0.f;
        for (int cc = 0; cc < 64; ++cc) s += sr[cc] * wq[cc * 512];
        att[q] = s * QSCALE * rescale[h];
    }
    __syncthreads();

    if (tid < 24) {
        float* row = att + tid * 64;
        float mx = row[0];
        for (int d = 1; d < 64; ++d) mx = fmaxf(mx, row[d]);
        float sum = 0.f;
        for (int d = 0; d < 64; ++d) { float e = expf(row[d] - mx); row[d] = e; sum += e; }
        float inv = 1.f / sum;
        for (int d = 0; d < 64; ++d) row[d] *= inv;
    }
    __syncthreads();

    for (int q = tid; q < 1536; q += 256) {
        int c = q & 63, ch = q >> 6;
        int h = ch / 3;
        const float* wv = Wv + c * 512 + h * 64;
        const float* ar = att + ch * 64;
        float s = 0.f;
        for (int d = 0; d < 64; ++d) s += ar[d] * wv[d];
        M_l[ch * 64 + c] = s;
    }
    __syncthreads();

    for (int q = tid; q < 1536; q += 256) {
        int c = q & 63, jo = q >> 6;
        float s = 0.f;
        #pragma unroll
        for (int k = 0; k < 3; ++k)
            #pragma unroll
            for (int h = 0; h < 8; ++h)
                s += M_l[(h * 3 + k) * 64 + c] * Wp[(k * 8 + h) * 24 + jo];
        Pt[b * 1536 + q] = s;
    }
}

// ---------------------------------------------------------------------------
// conv helpers: 8x8 tile, 192 threads, thread=(o, jj), sliding 3x3x8 register
// window, weights as wr[ic][di*3+dj] (OIHW-linear).
// ---------------------------------------------------------------------------
#define CONV_PROLOG(CWPTR)                                                    \
    const int tid = threadIdx.x;                                              \
    const int o = tid % 24, jj = tid / 24;                                    \
    const int blk = blockIdx.x;                                               \
    const int b = blk >> 8, ti = (blk >> 4) & 15, tj = blk & 15;              \
    const int i0 = ti * 8, j0 = tj * 8;                                       \
    const int g = o >> 3;                                                     \
    float wr[8][9];                                                           \
    {                                                                         \
        const float4* wp = (const float4*)((CWPTR) + o * 72);                 \
        _Pragma("unroll")                                                     \
        for (int t = 0; t < 18; ++t) ((float4*)wr)[t] = wp[t];                \
    }                                                                         \
    const int gj0 = j0 + jj - 1;                                              \
    const bool cok0 = gj0 >= 0;                                               \
    const bool cok2 = (j0 + jj + 1) < WW;

#define LOADROW(IN, GI, SLOT)                                                 \
    {                                                                         \
        const int gi_ = (GI);                                                 \
        const bool rok_ = (gi_ >= 0) & (gi_ < HH);                            \
        const float* rp_ = (IN) + (long)b * NN * 24 + g * 8                   \
                         + ((long)gi_ * WW + gj0) * 24;                       \
        float4 z_ = {0.f,0.f,0.f,0.f};                                        \
        float4 a0_=z_, a1_=z_, b0_=z_, b1_=z_, c0_=z_, c1_=z_;                \
        if (rok_ & cok0) { a0_ = *(const float4*)(rp_);                       \
                           a1_ = *(const float4*)(rp_ + 4); }                 \
        if (rok_)        { b0_ = *(const float4*)(rp_ + 24);                  \
                           b1_ = *(const float4*)(rp_ + 28); }                \
        if (rok_ & cok2) { c0_ = *(const float4*)(rp_ + 48);                  \
                           c1_ = *(const float4*)(rp_ + 52); }                \
        *(float4*)&win[SLOT][0][0] = a0_; *(float4*)&win[SLOT][0][4] = a1_;   \
        *(float4*)&win[SLOT][1][0] = b0_; *(float4*)&win[SLOT][1][4] = b1_;   \
        *(float4*)&win[SLOT][2][0] = c0_; *(float4*)&win[SLOT][2][4] = c1_;   \
    }

// K4: y1 = gelu(gconv(k_inp, c1w))
__global__ __launch_bounds__(192, 2) void conv1_gelu(
    const float* __restrict__ kin, const float* __restrict__ cw,
    float* __restrict__ y1)
{
    CONV_PROLOG(cw)
    float win[3][3][8];
    LOADROW(kin, i0 - 1, 0)
    LOADROW(kin, i0,     1)
    #pragma unroll
    for (int ii = 0; ii < 8; ++ii) {
        LOADROW(kin, i0 + ii + 1, (ii + 2) % 3)
        float s = 0.f;
        #pragma unroll
        for (int di = 0; di < 3; ++di) {
            const int slot = (ii + di) % 3;
            #pragma unroll
            for (int dj = 0; dj < 3; ++dj)
                #pragma unroll
                for (int ic = 0; ic < 8; ++ic)
                    s += win[slot][dj][ic] * wr[ic][di * 3 + dj];
        }
        s = 0.5f * s * (1.f + erff(s * 0.70710678f));
        y1[((long)((b * HH + i0 + ii) * WW + j0)) * 24 + tid] = s;
    }
}

// K5: out = fea @ P[b] + bp + gconv(y1, c2w)   (single store, no RMW)
__global__ __launch_bounds__(192, 2) void conv2_proj(
    const float* __restrict__ y1, const float* __restrict__ fea,
    const float* __restrict__ cw2, const float* __restrict__ Pt,
    const float* __restrict__ bp, float* __restrict__ outp)
{
    CONV_PROLOG(cw2)

    // projection: acc[ii] = bp[o] + sum_c fea[pix][c] * Pt[o][c]
    float acc[8];
    {
        const float bo = bp[o];
        #pragma unroll
        for (int ii = 0; ii < 8; ++ii) acc[ii] = bo;
        const float* PtRow = Pt + b * 1536 + o * 64;
        const float* feaB = fea + (((long)(b * HH + i0)) * WW + (j0 + jj)) * 64;
        for (int cq = 0; cq < 16; ++cq) {
            float4 p = *(const float4*)(PtRow + cq * 4);
            #pragma unroll
            for (int ii = 0; ii < 8; ++ii) {
                float4 f = *(const float4*)(feaB + (long)ii * WW * 64 + cq * 4);
                acc[ii] += f.x * p.x + f.y * p.y + f.z * p.z + f.w * p.w;
            }
        }
    }

    float win[3][3][8];
    LOADROW(y1, i0 - 1, 0)
    LOADROW(y1, i0,     1)
    #pragma unroll
    for (int ii = 0; ii < 8; ++ii) {
        LOADROW(y1, i0 + ii + 1, (ii + 2) % 3)
        float s = 0.f;
        #pragma unroll
        for (int di = 0; di < 3; ++di) {
            const int slot = (ii + di) % 3;
            #pragma unroll
            for (int dj = 0; dj < 3; ++dj)
                #pragma unroll
                for (int ic = 0; ic < 8; ++ic)
                    s += win[slot][dj][ic] * wr[ic][di * 3 + dj];
        }
        outp[((long)((b * HH + i0 + ii) * WW + j0)) * 24 + tid] = acc[ii] + s;
    }
}

// ---------------------------------------------------------------------------
extern "C" void kernel_launch(void* const* d_in, const int* in_sizes, int n_in,
                              void* d_out, int out_size, void* d_ws, size_t ws_size,
                              hipStream_t stream) {
    const float* x_in    = (const float*)d_in[0];
    const float* fea     = (const float*)d_in[1];
    const float* imap    = (const float*)d_in[2];
    const float* Wq      = (const float*)d_in[3];
    const float* Wk      = (const float*)d_in[4];
    const float* Wv      = (const float*)d_in[5];
    const float* rescale = (const float*)d_in[6];
    const float* Wp      = (const float*)d_in[7];
    const float* bp      = (const float*)d_in[8];
    const float* c1w     = (const float*)d_in[9];
    const float* c2w     = (const float*)d_in[10];
    float* out = (float*)d_out;

    float* ws      = (float*)d_ws;
    float* k_inp   = ws;                     // 1,572,864
    float* y1      = ws + 1572864;           // 1,572,864
    float* Sp_part = ws + 3145728;           // 512*1536 = 786,432
    float* Sp      = ws + 3932160;           // 6144
    float* Pt      = ws + 3938304;           // 6144

    s_reduce_kproj<<<512, 256, 0, stream>>>(imap, x_in, Wk, k_inp, Sp_part);
    sp_reduce<<<24, 256, 0, stream>>>(Sp_part, Sp);
    attn_p<<<4, 256, 0, stream>>>(Sp, Wk, Wq, Wv, rescale, Wp, Pt);
    conv1_gelu<<<BB * 256, 192, 0, stream>>>(k_inp, c1w, y1);
    conv2_proj<<<BB * 256, 192, 0, stream>>>(y1, fea, c2w, Pt, bp, out);
}